// Round 5
// baseline (4725.913 us; speedup 1.0000x reference)
//
#include <hip/hip_runtime.h>
#include <stdint.h>

typedef float  f32x4 __attribute__((ext_vector_type(4)));
typedef short  s16x8 __attribute__((ext_vector_type(8)));
typedef unsigned int u32;
typedef unsigned long long u64;
typedef unsigned short bfu;

#define B_ 256
#define T_ 256
#define I_ 128
#define H_ 512
#define O_ 128
#define CH 32          // timesteps per k2 launch
#define NCH (T_ / CH)

__device__ __forceinline__ bfu f2b(float f) {
    u32 u = __float_as_uint(f);
    u += 0x7fffu + ((u >> 16) & 1u);       // RNE
    return (bfu)(u >> 16);
}
__device__ __forceinline__ float b2f(bfu b) {
    return __uint_as_float(((u32)b) << 16);
}
__device__ __forceinline__ float sigf(float x) { return 1.f / (1.f + __expf(-x)); }
__device__ __forceinline__ float tanhfast(float x) { return 1.f - 2.f / (__expf(2.f * x) + 1.f); }

// ===========================================================================
// k_pack: weights -> MFMA B-fragment order, bf16.
// B-frag 16x16x32: lane L holds B[k = kt*32 + (L>>4)*8 + j][n = nt*16 + (L&15)].
// ===========================================================================
__global__ __launch_bounds__(256) void k_pack(
    const float* __restrict__ Wz, const float* __restrict__ Wr, const float* __restrict__ Wc,
    const float* __restrict__ Vz, const float* __restrict__ Vr, const float* __restrict__ Vc,
    const float* __restrict__ Wgh,
    const float* __restrict__ Uz, const float* __restrict__ Ur, const float* __restrict__ Uc,
    short* __restrict__ PW, short* __restrict__ PG, short* __restrict__ PU)
{
    int wv = blockIdx.x * 4 + (threadIdx.x >> 6);
    int L = threadIdx.x & 63;
    if (wv >= 2432) return;
    int koff = (L >> 4) << 3;
    const float* src; short* dst; int kbase, nt;
    if (wv < 768) {
        int g = wv >> 8, rem = wv & 255;
        int kt = rem >> 5; nt = rem & 31;
        src = (kt < 4) ? (g == 0 ? Wz : g == 1 ? Wr : Wc)
                       : (g == 0 ? Vz : g == 1 ? Vr : Vc);
        kbase = (kt & 3) * 32 + koff;
        dst = PW + ((size_t)(g * 256 + rem) * 64 + L) * 8;
    } else if (wv < 896) {
        int rem = wv - 768;
        nt = rem & 31;
        src = Wgh;
        kbase = (rem >> 5) * 32 + koff;
        dst = PG + ((size_t)rem * 64 + L) * 8;
    } else {
        int rem = wv - 896;
        int g = rem >> 9, r2 = rem & 511;
        nt = r2 & 31;
        src = (g == 0) ? Uz : (g == 1) ? Ur : Uc;
        kbase = (r2 >> 5) * 32 + koff;
        dst = PU + ((size_t)(g * 512 + r2) * 64 + L) * 8;
    }
    int n = nt * 16 + (L & 15);
    s16x8 v;
    #pragma unroll
    for (int j = 0; j < 8; ++j) v[j] = (short)f2b(src[(kbase + j) * H_ + n]);
    *(s16x8*)dst = v;
}

// ===========================================================================
// k1: input-side projections, bf16 outputs. Grid 512: b = idx>>1, half = idx&1
// (16-step tile within the CH=32 chunk). 512 threads = 8 waves x 64 cols.
// ===========================================================================
__global__ __launch_bounds__(512) void k1_mfma(
    const float* __restrict__ x, const float* __restrict__ dl,
    const float* __restrict__ mk, const float* __restrict__ xf,
    const float* __restrict__ bz, const float* __restrict__ br, const float* __restrict__ bc,
    const float* __restrict__ Bgh,
    const float* __restrict__ Wgx, const float* __restrict__ Bgx,
    const short* __restrict__ PW, const short* __restrict__ PG,
    bfu* __restrict__ pz, bfu* __restrict__ pr, bfu* __restrict__ pc,
    bfu* __restrict__ gm, int t0)
{
    __shared__ short Abuf[12 * 64 * 8];
    const int tid = threadIdx.x;
    const int L = tid & 63;
    const int w = tid >> 6;
    const int b = blockIdx.x >> 1;
    const int half = blockIdx.x & 1;

    for (int c = tid; c < 12 * 64; c += 512) {
        int Ls = c & 63, kt = c >> 6;
        int tl = Ls & 15, q = Ls >> 4;
        int gbase = (b * T_ + t0 + half * 16 + tl) * I_;
        s16x8 v;
        if (kt < 4) {
            int kb = kt * 32 + q * 8;
            #pragma unroll
            for (int j = 0; j < 8; ++j) {
                int k = kb + j, gi = gbase + k;
                float mv = mk[gi];
                float dx = dl[gi] * Wgx[k] + Bgx[k];
                float xr = dx * xf[gi] + (1.f - dx) * 0.001f;
                v[j] = (short)f2b((mv > 0.5f) ? xr : x[gi]);
            }
        } else if (kt < 8) {
            int kb = (kt - 4) * 32 + q * 8;
            #pragma unroll
            for (int j = 0; j < 8; ++j) v[j] = (short)f2b(1.f - mk[gbase + kb + j]);
        } else {
            int kb = (kt - 8) * 32 + q * 8;
            #pragma unroll
            for (int j = 0; j < 8; ++j) v[j] = (short)f2b(mk[gbase + kb + j]);
        }
        *(s16x8*)&Abuf[(size_t)c * 8] = v;
    }
    __syncthreads();

    const s16x8* PWf = (const s16x8*)PW;
    const s16x8* PGf = (const s16x8*)PG;

    for (int g = 0; g < 3; ++g) {
        f32x4 acc[4];
        #pragma unroll
        for (int nt = 0; nt < 4; ++nt) acc[nt] = (f32x4)0.f;
        for (int kt = 0; kt < 8; ++kt) {
            s16x8 a = *(const s16x8*)&Abuf[(kt * 64 + L) * 8];
            const s16x8* pw = PWf + ((size_t)(g * 256 + kt * 32 + w * 4) * 64 + L);
            #pragma unroll
            for (int nt = 0; nt < 4; ++nt)
                acc[nt] = __builtin_amdgcn_mfma_f32_16x16x32_bf16(a, pw[(size_t)nt * 64], acc[nt], 0, 0, 0);
        }
        const float* bias = (g == 0) ? bz : (g == 1) ? br : bc;
        bfu* dst = (g == 0) ? pz : (g == 1) ? pr : pc;
        #pragma unroll
        for (int nt = 0; nt < 4; ++nt) {
            int n = w * 64 + nt * 16 + (L & 15);
            float bv = bias[n];
            #pragma unroll
            for (int reg = 0; reg < 4; ++reg) {
                int tl = half * 16 + (L >> 4) * 4 + reg;
                dst[(size_t)(tl * B_ + b) * H_ + n] = f2b(acc[nt][reg] + bv);
            }
        }
    }
    {
        f32x4 acc[4];
        #pragma unroll
        for (int nt = 0; nt < 4; ++nt) acc[nt] = (f32x4)0.f;
        for (int kk = 0; kk < 4; ++kk) {
            s16x8 a = *(const s16x8*)&Abuf[((8 + kk) * 64 + L) * 8];
            const s16x8* pg = PGf + ((size_t)(kk * 32 + w * 4) * 64 + L);
            #pragma unroll
            for (int nt = 0; nt < 4; ++nt)
                acc[nt] = __builtin_amdgcn_mfma_f32_16x16x32_bf16(a, pg[(size_t)nt * 64], acc[nt], 0, 0, 0);
        }
        #pragma unroll
        for (int nt = 0; nt < 4; ++nt) {
            int n = w * 64 + nt * 16 + (L & 15);
            float bv = Bgh[n];
            #pragma unroll
            for (int reg = 0; reg < 4; ++reg) {
                int tl = half * 16 + (L >> 4) * 4 + reg;
                gm[(size_t)(tl * B_ + b) * H_ + n] = f2b(__expf(-fmaxf(acc[nt][reg] + bv, 0.f)));
            }
        }
    }
}

// ===========================================================================
// k2_dist: distributed scan. 256 blocks x 256 threads (1/CU via 104 KB LDS).
// Group g = 16 col-blocks j, batch rows [16g,16g+16). Block j owns cols
// [32j,32j+32); its U-slice (96 KB bf16) lives in LDS for the whole launch.
// Per step: group exchanges A / (A*r) fragments (16 KB) via agent-scope
// stores/loads; epoch counters (monotonic, memset per launch) gate phases.
// ===========================================================================
__global__ __launch_bounds__(256) void k2_dist(
    const bfu* __restrict__ pz, const bfu* __restrict__ pr,
    const bfu* __restrict__ pc, const bfu* __restrict__ gmA,
    const short* __restrict__ PU, short* __restrict__ Afrag, short* __restrict__ Arfrag,
    u32* __restrict__ cnt, float* __restrict__ hws)
{
    __shared__ short Us[6144 * 8];       // 96 KB: [gate*32 + kt*2 + nt][lane][8]
    __shared__ float red[4 * 64 * 8];    // 8 KB reduce scratch
    const int tid = threadIdx.x, L = tid & 63, w = tid >> 6;
    const int g = blockIdx.x >> 4, j = blockIdx.x & 15;
    const int nt = w & 1, kh = w >> 1;
    const int b0 = g * 16;

    for (int u = tid; u < 6144; u += 256) {
        int fl = u >> 6, Lc = u & 63;
        int gate = fl >> 5, rem = fl & 31, kt = rem >> 1, ntl = rem & 1;
        *(s16x8*)&Us[(size_t)u * 8] =
            *(const s16x8*)&PU[((size_t)(gate * 512 + kt * 32 + 2 * j + ntl) * 64 + Lc) * 8];
    }

    const int n_own = j * 32 + nt * 16 + (L & 15);
    const int row0 = (L >> 4) * 4;
    const int kt2 = n_own >> 5, q2 = (n_own >> 3) & 3, jj = n_own & 7;
    short* Aslot  = Afrag  + (size_t)(g * 16 + kt2) * 512;
    short* Arslot = Arfrag + (size_t)(g * 16 + kt2) * 512;
    u32* cg = cnt + g * 16;              // 64 B stride per group
    __syncthreads();

    // init: A = gm[tl=0] * h
    float A32[4];
    #pragma unroll
    for (int reg = 0; reg < 4; ++reg) {
        int row = row0 + reg;
        float h = hws[(size_t)(b0 + row) * H_ + n_own];
        float gv = b2f(gmA[(size_t)(b0 + row) * H_ + n_own]);
        A32[reg] = gv * h;
        if (kh == 0)
            __hip_atomic_store(&Aslot[((row | (q2 << 4))) * 8 + jj], (short)f2b(A32[reg]),
                               __ATOMIC_RELAXED, __HIP_MEMORY_SCOPE_AGENT);
    }
    __builtin_amdgcn_s_waitcnt(0);
    __syncthreads();
    if (tid == 0) __hip_atomic_fetch_add(cg, 1u, __ATOMIC_RELEASE, __HIP_MEMORY_SCOPE_AGENT);
    u32 target = 16;

    for (int tl = 0; tl < CH; ++tl) {
        // prefetch own pre-activations (independent of exchange)
        float lpz[4], lpr[4], lpc[4], lgm[4];
        int tln = (tl + 1 < CH) ? tl + 1 : tl;
        #pragma unroll
        for (int reg = 0; reg < 4; ++reg) {
            int row = row0 + reg;
            size_t ix = (size_t)(tl * B_ + b0 + row) * H_ + n_own;
            lpz[reg] = b2f(pz[ix]); lpr[reg] = b2f(pr[ix]); lpc[reg] = b2f(pc[ix]);
            lgm[reg] = b2f(gmA[(size_t)(tln * B_ + b0 + row) * H_ + n_own]);
        }
        if (tid == 0) {
            long gd = 50000000;
            while (__hip_atomic_load(cg, __ATOMIC_ACQUIRE, __HIP_MEMORY_SCOPE_AGENT) < target && --gd) ;
        }
        __syncthreads();

        // ---- phase 1: z,r partial GEMM (kh half of k) ----
        u64 av[8][2];
        #pragma unroll
        for (int kk = 0; kk < 8; ++kk) {
            int kt = kh * 8 + kk;
            u64* ap = (u64*)(Afrag + (size_t)(g * 16 + kt) * 512 + L * 8);
            av[kk][0] = __hip_atomic_load(ap,     __ATOMIC_RELAXED, __HIP_MEMORY_SCOPE_AGENT);
            av[kk][1] = __hip_atomic_load(ap + 1, __ATOMIC_RELAXED, __HIP_MEMORY_SCOPE_AGENT);
        }
        f32x4 accz = (f32x4)0.f, accr = (f32x4)0.f;
        #pragma unroll
        for (int kk = 0; kk < 8; ++kk) {
            int kt = kh * 8 + kk;
            union { s16x8 v; u64 q[2]; } ua;
            ua.q[0] = av[kk][0]; ua.q[1] = av[kk][1];
            s16x8 bz = *(const s16x8*)&Us[(size_t)((0 * 32 + kt * 2 + nt) * 64 + L) * 8];
            s16x8 br = *(const s16x8*)&Us[(size_t)((1 * 32 + kt * 2 + nt) * 64 + L) * 8];
            accz = __builtin_amdgcn_mfma_f32_16x16x32_bf16(ua.v, bz, accz, 0, 0, 0);
            accr = __builtin_amdgcn_mfma_f32_16x16x32_bf16(ua.v, br, accr, 0, 0, 0);
        }
        *(f32x4*)&red[(w * 64 + L) * 8 + 0] = accz;
        *(f32x4*)&red[(w * 64 + L) * 8 + 4] = accr;
        __syncthreads();
        accz += *(const f32x4*)&red[((w ^ 2) * 64 + L) * 8 + 0];
        accr += *(const f32x4*)&red[((w ^ 2) * 64 + L) * 8 + 4];
        float zz[4];
        #pragma unroll
        for (int reg = 0; reg < 4; ++reg) {
            float z = sigf(accz[reg] + lpz[reg]);
            float r = sigf(accr[reg] + lpr[reg]);
            zz[reg] = z;
            if (kh == 0)
                __hip_atomic_store(&Arslot[((row0 + reg) | (q2 << 4)) * 8 + jj], (short)f2b(A32[reg] * r),
                                   __ATOMIC_RELAXED, __HIP_MEMORY_SCOPE_AGENT);
        }
        __builtin_amdgcn_s_waitcnt(0);
        __syncthreads();
        if (tid == 0) __hip_atomic_fetch_add(cg, 1u, __ATOMIC_RELEASE, __HIP_MEMORY_SCOPE_AGENT);
        target += 16;
        if (tid == 0) {
            long gd = 50000000;
            while (__hip_atomic_load(cg, __ATOMIC_ACQUIRE, __HIP_MEMORY_SCOPE_AGENT) < target && --gd) ;
        }
        __syncthreads();

        // ---- phase 2: c partial GEMM + state update ----
        #pragma unroll
        for (int kk = 0; kk < 8; ++kk) {
            int kt = kh * 8 + kk;
            u64* ap = (u64*)(Arfrag + (size_t)(g * 16 + kt) * 512 + L * 8);
            av[kk][0] = __hip_atomic_load(ap,     __ATOMIC_RELAXED, __HIP_MEMORY_SCOPE_AGENT);
            av[kk][1] = __hip_atomic_load(ap + 1, __ATOMIC_RELAXED, __HIP_MEMORY_SCOPE_AGENT);
        }
        f32x4 accc = (f32x4)0.f;
        #pragma unroll
        for (int kk = 0; kk < 8; ++kk) {
            int kt = kh * 8 + kk;
            union { s16x8 v; u64 q[2]; } ua;
            ua.q[0] = av[kk][0]; ua.q[1] = av[kk][1];
            s16x8 bc = *(const s16x8*)&Us[(size_t)((2 * 32 + kt * 2 + nt) * 64 + L) * 8];
            accc = __builtin_amdgcn_mfma_f32_16x16x32_bf16(ua.v, bc, accc, 0, 0, 0);
        }
        *(f32x4*)&red[(w * 64 + L) * 8 + 0] = accc;
        __syncthreads();
        accc += *(const f32x4*)&red[((w ^ 2) * 64 + L) * 8 + 0];
        #pragma unroll
        for (int reg = 0; reg < 4; ++reg) {
            float c = tanhfast(accc[reg] + lpc[reg]);
            float h = (1.f - zz[reg]) * A32[reg] + zz[reg] * c;
            if (tl < CH - 1) {
                A32[reg] = lgm[reg] * h;
                if (kh == 0)
                    __hip_atomic_store(&Aslot[((row0 + reg) | (q2 << 4)) * 8 + jj], (short)f2b(A32[reg]),
                                       __ATOMIC_RELAXED, __HIP_MEMORY_SCOPE_AGENT);
            } else if (kh == 0) {
                hws[(size_t)(b0 + row0 + reg) * H_ + n_own] = h;
            }
        }
        if (tl < CH - 1) {
            __builtin_amdgcn_s_waitcnt(0);
            __syncthreads();
            if (tid == 0) __hip_atomic_fetch_add(cg, 1u, __ATOMIC_RELEASE, __HIP_MEMORY_SCOPE_AGENT);
            target += 16;
        }
    }
}

// ===========================================================================
// k3: BatchNorm(eval) + decoder GEMV + log_softmax.
// ===========================================================================
__global__ __launch_bounds__(128) void k3_out(
    const float* __restrict__ hws,
    const float* __restrict__ dW, const float* __restrict__ db,
    const float* __restrict__ bng, const float* __restrict__ bnb,
    float* __restrict__ out)
{
    __shared__ float hb[H_];
    __shared__ float red[O_];
    const int tid = threadIdx.x;
    const int b = blockIdx.x;
    const float s = 0.9999950000374997f;   // 1/sqrt(1 + 1e-5)
    for (int k = tid; k < H_; k += O_) {
        float v = hws[(size_t)b * H_ + k] * s * bng[k] + bnb[k];
        hb[k] = v;
        out[B_ * O_ + (size_t)b * H_ + k] = v;
    }
    __syncthreads();
    float acc = db[tid];
    #pragma unroll 4
    for (int k = 0; k < H_; ++k) acc += hb[k] * dW[(size_t)k * O_ + tid];
    red[tid] = acc;
    __syncthreads();
    for (int sh = 64; sh > 0; sh >>= 1) {
        if (tid < sh) red[tid] = fmaxf(red[tid], red[tid + sh]);
        __syncthreads();
    }
    float mx = red[0];
    __syncthreads();
    red[tid] = __expf(acc - mx);
    __syncthreads();
    for (int sh = 64; sh > 0; sh >>= 1) {
        if (tid < sh) red[tid] += red[tid + sh];
        __syncthreads();
    }
    float lse = __logf(red[0]) + mx;
    out[(size_t)b * O_ + tid] = acc - lse;
}

extern "C" void kernel_launch(void* const* d_in, const int* in_sizes, int n_in,
                              void* d_out, int out_size, void* d_ws, size_t ws_size,
                              hipStream_t stream)
{
    (void)in_sizes; (void)n_in; (void)out_size; (void)ws_size;
    const float* x   = (const float*)d_in[0];
    const float* dl  = (const float*)d_in[1];
    const float* m   = (const float*)d_in[2];
    const float* xf  = (const float*)d_in[3];
    const float* Wr  = (const float*)d_in[4];
    const float* Ur  = (const float*)d_in[5];
    const float* Vr  = (const float*)d_in[6];
    const float* br  = (const float*)d_in[7];
    const float* Wz  = (const float*)d_in[8];
    const float* Uz  = (const float*)d_in[9];
    const float* Vz  = (const float*)d_in[10];
    const float* bz  = (const float*)d_in[11];
    const float* Wc  = (const float*)d_in[12];
    const float* Uc  = (const float*)d_in[13];
    const float* Vc  = (const float*)d_in[14];
    const float* bc  = (const float*)d_in[15];
    const float* Wgx = (const float*)d_in[16];
    const float* Bgx = (const float*)d_in[17];
    const float* Wgh = (const float*)d_in[18];
    const float* Bgh = (const float*)d_in[19];
    const float* dW  = (const float*)d_in[20];
    const float* db  = (const float*)d_in[21];
    const float* bng = (const float*)d_in[22];
    const float* bnb = (const float*)d_in[23];

    char* ws = (char*)d_ws;
    short* PW = (short*)ws;                            // 768 KB
    short* PG = PW + 3 * 256 * 64 * 8;                 // 128 KB
    short* PU = PG + 128 * 64 * 8;                     // 1.5 MB
    short* Afrag  = PU + 3 * 512 * 64 * 8;             // 256 KB
    short* Arfrag = Afrag + 16 * 16 * 64 * 8;          // 256 KB
    u32*   cnt    = (u32*)(Arfrag + 16 * 16 * 64 * 8); // 1 KB (16 groups x 64B)
    bfu* pz  = (bfu*)(cnt + 256);
    const size_t SZ = (size_t)CH * B_ * H_;            // elems per bf16 chunk array
    bfu* pr  = pz + SZ;
    bfu* pc  = pr + SZ;
    bfu* gmA = pc + SZ;
    float* hws = (float*)(gmA + SZ);                   // fp32 [B,H]

    hipMemsetAsync(hws, 0, (size_t)B_ * H_ * sizeof(float), stream);
    k_pack<<<dim3(608), dim3(256), 0, stream>>>(Wz, Wr, Wc, Vz, Vr, Vc, Wgh,
                                                Uz, Ur, Uc, PW, PG, PU);
    for (int c = 0; c < NCH; ++c) {
        k1_mfma<<<dim3(B_ * 2), dim3(512), 0, stream>>>(
            x, dl, m, xf, bz, br, bc, Bgh, Wgx, Bgx, PW, PG,
            pz, pr, pc, gmA, c * CH);
        hipMemsetAsync(cnt, 0, 1024, stream);
        k2_dist<<<dim3(256), dim3(256), 0, stream>>>(
            pz, pr, pc, gmA, PU, Afrag, Arfrag, cnt, hws);
    }
    k3_out<<<dim3(B_), dim3(O_), 0, stream>>>(hws, dW, db, bng, bnb, (float*)d_out);
}

// Round 6
// 4278.019 us; speedup vs baseline: 1.1047x; 1.1047x over previous
//
#include <hip/hip_runtime.h>
#include <stdint.h>

typedef float  f32x4 __attribute__((ext_vector_type(4)));
typedef short  s16x8 __attribute__((ext_vector_type(8)));
typedef unsigned int u32;
typedef unsigned short bfu;
typedef long long i64;

#define B_ 256
#define T_ 256
#define I_ 128
#define H_ 512
#define O_ 128
#define CH 16
#define NCH (T_ / CH)
#define SLOTS ((size_t)CH * B_ * H_)   // elems per bf16 pre-array

__device__ __forceinline__ bfu f2b(float f) {
    u32 u = __float_as_uint(f);
    u += 0x7fffu + ((u >> 16) & 1u);
    return (bfu)(u >> 16);
}
__device__ __forceinline__ float b2f(bfu b) { return __uint_as_float(((u32)b) << 16); }
__device__ __forceinline__ float sigf(float x) { return 1.f / (1.f + __expf(-x)); }
__device__ __forceinline__ float tanhfast(float x) { return 1.f - 2.f / (__expf(2.f * x) + 1.f); }

// software float -> OCP e4m3fn, RNE, saturating
__device__ __forceinline__ unsigned char f2e4m3(float f) {
    u32 u = __float_as_uint(f);
    u32 s = (u >> 24) & 0x80u;
    u &= 0x7fffffffu;
    if (u >= 0x43e00000u) return (unsigned char)(s | 0x7eu);    // >= 448 -> sat
    if (u < 0x3c800000u) {                                       // < 2^-6 -> subnormal
        int m = __float2int_rn(__uint_as_float(u) * 512.f);
        if (m >= 8) return (unsigned char)(s | 0x08u);
        return (unsigned char)(s | (u32)m);
    }
    u += 0x7ffffu + ((u >> 20) & 1u);                            // RNE at bit 20
    u32 e8 = ((u >> 23) & 0xffu) - 120u;                         // bias 127 -> 7
    return (unsigned char)(s | (e8 << 3) | ((u >> 20) & 7u));
}

// ===========================================================================
// k_pack: weights -> MFMA B-fragment order.
// frag 16x16x32: lane L holds B[k = kt*32 + (L>>4)*8 + j][n = nt*16 + (L&15)].
// PW bf16 (W|V per gate), PG bf16 (Wgh), PUc bf16 (Uc), PU8 fp8 (Uz,Ur x32).
// ===========================================================================
__global__ __launch_bounds__(256) void k_pack(
    const float* __restrict__ Wz, const float* __restrict__ Wr, const float* __restrict__ Wc,
    const float* __restrict__ Vz, const float* __restrict__ Vr, const float* __restrict__ Vc,
    const float* __restrict__ Wgh,
    const float* __restrict__ Uz, const float* __restrict__ Ur, const float* __restrict__ Uc,
    short* __restrict__ PW, short* __restrict__ PG, short* __restrict__ PUc,
    unsigned char* __restrict__ PU8)
{
    int wv = blockIdx.x * 4 + (threadIdx.x >> 6);
    int L = threadIdx.x & 63;
    if (wv >= 2432) return;
    int koff = (L >> 4) << 3;
    int ncol;
    if (wv < 768) {                       // PW: gate x (kt<4:W, kt>=4:V)
        int g = wv >> 8, rem = wv & 255;
        int kt = rem >> 5; ncol = (rem & 31) * 16 + (L & 15);
        const float* src = (kt < 4) ? (g == 0 ? Wz : g == 1 ? Wr : Wc)
                                    : (g == 0 ? Vz : g == 1 ? Vr : Vc);
        int kbase = (kt & 3) * 32 + koff;
        s16x8 v;
        #pragma unroll
        for (int j = 0; j < 8; ++j) v[j] = (short)f2b(src[(kbase + j) * H_ + ncol]);
        *(s16x8*)&PW[((size_t)(g * 256 + rem) * 64 + L) * 8] = v;
    } else if (wv < 896) {                // PG
        int rem = wv - 768;
        ncol = (rem & 31) * 16 + (L & 15);
        int kbase = (rem >> 5) * 32 + koff;
        s16x8 v;
        #pragma unroll
        for (int j = 0; j < 8; ++j) v[j] = (short)f2b(Wgh[(kbase + j) * H_ + ncol]);
        *(s16x8*)&PG[((size_t)rem * 64 + L) * 8] = v;
    } else if (wv < 1408) {               // PUc bf16
        int rem = wv - 896;               // kt*32+nt, kt 0..15
        ncol = (rem & 31) * 16 + (L & 15);
        int kbase = (rem >> 5) * 32 + koff;
        s16x8 v;
        #pragma unroll
        for (int j = 0; j < 8; ++j) v[j] = (short)f2b(Uc[(kbase + j) * H_ + ncol]);
        *(s16x8*)&PUc[((size_t)rem * 64 + L) * 8] = v;
    } else {                              // PU8: Uz, Ur scaled x32, e4m3
        int rem = wv - 1408;              // g*512 + kt*32 + nt
        int g = rem >> 9, r2 = rem & 511;
        ncol = (r2 & 31) * 16 + (L & 15);
        int kbase = (r2 >> 5) * 32 + koff;
        const float* src = (g == 0) ? Uz : Ur;
        unsigned char* d = PU8 + ((size_t)rem * 64 + L) * 8;
        #pragma unroll
        for (int j = 0; j < 8; ++j) d[j] = f2e4m3(src[(kbase + j) * H_ + ncol] * 32.f);
    }
}

// ===========================================================================
// k1 unit: input-side projections for one batch row b, 16 timesteps.
// 512 threads (8 waves x 64 cols). bf16 outputs, layout [tl][b][H].
// ===========================================================================
__device__ void k1_unit(char* sm, int b, int t0,
    const float* __restrict__ x, const float* __restrict__ dl,
    const float* __restrict__ mk, const float* __restrict__ xf,
    const float* __restrict__ bz, const float* __restrict__ br, const float* __restrict__ bc,
    const float* __restrict__ Bgh,
    const float* __restrict__ Wgx, const float* __restrict__ Bgx,
    const short* __restrict__ PW, const short* __restrict__ PG,
    bfu* __restrict__ pz, bfu* __restrict__ pr, bfu* __restrict__ pc, bfu* __restrict__ gm)
{
    short* Abuf = (short*)sm;             // 12 KB: [kt 0..11][lane][8]
    const int t = threadIdx.x & 511;
    const int L = t & 63, w = t >> 6;

    for (int cc = t; cc < 12 * 64; cc += 512) {
        int Ls = cc & 63, kt = cc >> 6;
        int tl = Ls & 15, q = Ls >> 4;
        int gbase = (b * T_ + t0 + tl) * I_;
        s16x8 v;
        if (kt < 4) {
            int kb = kt * 32 + q * 8;
            #pragma unroll
            for (int j = 0; j < 8; ++j) {
                int k = kb + j, gi = gbase + k;
                float mv = mk[gi];
                float dx = dl[gi] * Wgx[k] + Bgx[k];
                float xr = dx * xf[gi] + (1.f - dx) * 0.001f;
                v[j] = (short)f2b((mv > 0.5f) ? xr : x[gi]);
            }
        } else if (kt < 8) {
            int kb = (kt - 4) * 32 + q * 8;
            #pragma unroll
            for (int j = 0; j < 8; ++j) v[j] = (short)f2b(1.f - mk[gbase + kb + j]);
        } else {
            int kb = (kt - 8) * 32 + q * 8;
            #pragma unroll
            for (int j = 0; j < 8; ++j) v[j] = (short)f2b(mk[gbase + kb + j]);
        }
        *(s16x8*)&Abuf[(size_t)cc * 8] = v;
    }
    __syncthreads();

    const s16x8* PWf = (const s16x8*)PW;
    const s16x8* PGf = (const s16x8*)PG;

    for (int g = 0; g < 3; ++g) {
        f32x4 acc[4];
        #pragma unroll
        for (int nt = 0; nt < 4; ++nt) acc[nt] = (f32x4)0.f;
        for (int kt = 0; kt < 8; ++kt) {
            s16x8 a = *(const s16x8*)&Abuf[(kt * 64 + L) * 8];
            const s16x8* pw = PWf + ((size_t)(g * 256 + kt * 32 + w * 4) * 64 + L);
            #pragma unroll
            for (int nt = 0; nt < 4; ++nt)
                acc[nt] = __builtin_amdgcn_mfma_f32_16x16x32_bf16(a, pw[(size_t)nt * 64], acc[nt], 0, 0, 0);
        }
        const float* bias = (g == 0) ? bz : (g == 1) ? br : bc;
        bfu* dst = (g == 0) ? pz : (g == 1) ? pr : pc;
        #pragma unroll
        for (int nt = 0; nt < 4; ++nt) {
            int n = w * 64 + nt * 16 + (L & 15);
            float bv = bias[n];
            #pragma unroll
            for (int reg = 0; reg < 4; ++reg) {
                int tl = (L >> 4) * 4 + reg;
                dst[(size_t)(tl * B_ + b) * H_ + n] = f2b(acc[nt][reg] + bv);
            }
        }
    }
    {
        f32x4 acc[4];
        #pragma unroll
        for (int nt = 0; nt < 4; ++nt) acc[nt] = (f32x4)0.f;
        for (int kk = 0; kk < 4; ++kk) {
            s16x8 a = *(const s16x8*)&Abuf[((8 + kk) * 64 + L) * 8];
            const s16x8* pg = PGf + ((size_t)(kk * 32 + w * 4) * 64 + L);
            #pragma unroll
            for (int nt = 0; nt < 4; ++nt)
                acc[nt] = __builtin_amdgcn_mfma_f32_16x16x32_bf16(a, pg[(size_t)nt * 64], acc[nt], 0, 0, 0);
        }
        #pragma unroll
        for (int nt = 0; nt < 4; ++nt) {
            int n = w * 64 + nt * 16 + (L & 15);
            float bv = Bgh[n];
            #pragma unroll
            for (int reg = 0; reg < 4; ++reg) {
                int tl = (L >> 4) * 4 + reg;
                gm[(size_t)(tl * B_ + b) * H_ + n] = f2b(__expf(-fmaxf(acc[nt][reg] + bv, 0.f)));
            }
        }
    }
}

// ===========================================================================
// scan block: 1024 threads, 16 batch rows [16g, 16g+16), 16 steps.
// z/r GEMMs in fp8 (A x64, U x32, unscale 1/2048); c GEMM bf16.
// ===========================================================================
__device__ void scan_block(char* sm, int g, const bfu* __restrict__ pre,
                           const short* __restrict__ PUc, const unsigned char* __restrict__ PU8,
                           float* __restrict__ hws)
{
    char* Abf8 = sm;                        // 8 KB fp8 A-fragments [kt][lane][8]
    short* Apbf = (short*)(sm + 8192);      // 16 KB bf16 (A*r)-fragments
    const bfu* pz = pre;
    const bfu* pr = pre + SLOTS;
    const bfu* pc = pre + 2 * SLOTS;
    const bfu* gm = pre + 3 * SLOTS;
    const int tid = threadIdx.x, L = tid & 63, w = tid >> 6;
    const int b0 = g * 16;
    const i64* PU8q = (const i64*)PU8;
    const s16x8* PUcf = (const s16x8*)PUc;
    const float INV = 4.8828125e-4f;        // 1/2048

    int nn[2], ktq[2], lsh[2], j2;
    #pragma unroll
    for (int nt = 0; nt < 2; ++nt) {
        nn[nt] = w * 32 + nt * 16 + (L & 15);
        ktq[nt] = nn[nt] >> 5;
        lsh[nt] = ((nn[nt] >> 3) & 3) << 4;
    }
    j2 = nn[0] & 7;
    const int row0 = (L >> 4) * 4;

    float A32[2][4];
    #pragma unroll
    for (int nt = 0; nt < 2; ++nt)
        #pragma unroll
        for (int reg = 0; reg < 4; ++reg) {
            int row = row0 + reg;
            float h = hws[(size_t)(b0 + row) * H_ + nn[nt]];
            float gv = b2f(gm[(size_t)(b0 + row) * H_ + nn[nt]]);   // tl = 0
            float A = gv * h;
            A32[nt][reg] = A;
            Abf8[(ktq[nt] * 64 + (row | lsh[nt])) * 8 + j2] = f2e4m3(A * 64.f);
        }
    __syncthreads();

    for (int tl = 0; tl < CH; ++tl) {
        float lpz[2][4], lpr[2][4], lpc[2][4], lgm[2][4];
        int tln = (tl + 1 < CH) ? tl + 1 : tl;
        #pragma unroll
        for (int nt = 0; nt < 2; ++nt)
            #pragma unroll
            for (int reg = 0; reg < 4; ++reg) {
                int row = b0 + row0 + reg;
                size_t ix = (size_t)(tl * B_ + row) * H_ + nn[nt];
                lpz[nt][reg] = b2f(pz[ix]);
                lpr[nt][reg] = b2f(pr[ix]);
                lpc[nt][reg] = b2f(pc[ix]);
                lgm[nt][reg] = b2f(gm[(size_t)(tln * B_ + row) * H_ + nn[nt]]);
            }

        // ---- phase 1: z,r fp8 GEMMs ----
        f32x4 az[2], ar[2];
        az[0] = (f32x4)0.f; az[1] = (f32x4)0.f;
        ar[0] = (f32x4)0.f; ar[1] = (f32x4)0.f;
        #pragma unroll 4
        for (int kt = 0; kt < 16; ++kt) {
            i64 a8 = *(const i64*)&Abf8[(kt * 64 + L) * 8];
            const i64* z8 = PU8q + ((size_t)(0 * 512 + kt * 32 + w * 2) * 64 + L);
            const i64* r8 = PU8q + ((size_t)(1 * 512 + kt * 32 + w * 2) * 64 + L);
            i64 bz0 = z8[0], bz1 = z8[64], br0 = r8[0], br1 = r8[64];
            az[0] = __builtin_amdgcn_mfma_f32_16x16x32_fp8_fp8(a8, bz0, az[0], 0, 0, 0);
            az[1] = __builtin_amdgcn_mfma_f32_16x16x32_fp8_fp8(a8, bz1, az[1], 0, 0, 0);
            ar[0] = __builtin_amdgcn_mfma_f32_16x16x32_fp8_fp8(a8, br0, ar[0], 0, 0, 0);
            ar[1] = __builtin_amdgcn_mfma_f32_16x16x32_fp8_fp8(a8, br1, ar[1], 0, 0, 0);
        }
        float zv[2][4];
        #pragma unroll
        for (int nt = 0; nt < 2; ++nt)
            #pragma unroll
            for (int reg = 0; reg < 4; ++reg) {
                float z = sigf(az[nt][reg] * INV + lpz[nt][reg]);
                float r = sigf(ar[nt][reg] * INV + lpr[nt][reg]);
                zv[nt][reg] = z;
                Apbf[(ktq[nt] * 64 + ((row0 + reg) | lsh[nt])) * 8 + j2] = (short)f2b(A32[nt][reg] * r);
            }
        __syncthreads();

        // ---- phase 2: c bf16 GEMM + state update ----
        f32x4 ac[2];
        ac[0] = (f32x4)0.f; ac[1] = (f32x4)0.f;
        #pragma unroll 4
        for (int kt = 0; kt < 16; ++kt) {
            s16x8 a = *(const s16x8*)&Apbf[(kt * 64 + L) * 8];
            const s16x8* c8 = PUcf + ((size_t)(kt * 32 + w * 2) * 64 + L);
            s16x8 bc0 = c8[0], bc1 = c8[64];
            ac[0] = __builtin_amdgcn_mfma_f32_16x16x32_bf16(a, bc0, ac[0], 0, 0, 0);
            ac[1] = __builtin_amdgcn_mfma_f32_16x16x32_bf16(a, bc1, ac[1], 0, 0, 0);
        }
        #pragma unroll
        for (int nt = 0; nt < 2; ++nt)
            #pragma unroll
            for (int reg = 0; reg < 4; ++reg) {
                int row = row0 + reg;
                float cc = tanhfast(ac[nt][reg] + lpc[nt][reg]);
                float z = zv[nt][reg];
                float hn = (1.f - z) * A32[nt][reg] + z * cc;
                if (tl < CH - 1) {
                    float An = lgm[nt][reg] * hn;
                    A32[nt][reg] = An;
                    Abf8[(ktq[nt] * 64 + (row | lsh[nt])) * 8 + j2] = f2e4m3(An * 64.f);
                } else {
                    hws[(size_t)(b0 + row) * H_ + nn[nt]] = hn;
                }
            }
        __syncthreads();
    }
}

// ===========================================================================
// fused launch: blocks 0-15 scan chunk c-1; blocks 16-143 (2x512-thr units)
// compute pre-activations for chunk c into the other buffer.
// ===========================================================================
__global__ __launch_bounds__(1024) void k_fused(int c,
    const float* __restrict__ x, const float* __restrict__ dl,
    const float* __restrict__ mk, const float* __restrict__ xf,
    const float* __restrict__ bz, const float* __restrict__ br, const float* __restrict__ bc,
    const float* __restrict__ Bgh,
    const float* __restrict__ Wgx, const float* __restrict__ Bgx,
    const short* __restrict__ PW, const short* __restrict__ PG,
    const short* __restrict__ PUc, const unsigned char* __restrict__ PU8,
    bfu* __restrict__ buf0, bfu* __restrict__ buf1, float* __restrict__ hws)
{
    __shared__ char sm[24576];
    if (blockIdx.x < 16) {
        if (c == 0) return;
        const bfu* pre = (c & 1) ? buf0 : buf1;    // chunk c-1 lives in buf[(c-1)&1]
        scan_block(sm, blockIdx.x, pre, PUc, PU8, hws);
    } else {
        if (c >= NCH) return;
        int unit = (blockIdx.x - 16) * 2 + (threadIdx.x >> 9);
        if (unit >= B_) return;                     // whole block idle for blockIdx >= 144
        bfu* dst = (c & 1) ? buf1 : buf0;           // chunk c -> buf[c&1]
        k1_unit(sm + (threadIdx.x >> 9) * 12288, unit, c * CH,
                x, dl, mk, xf, bz, br, bc, Bgh, Wgx, Bgx, PW, PG,
                dst, dst + SLOTS, dst + 2 * SLOTS, dst + 3 * SLOTS);
    }
}

// ===========================================================================
// k3: BatchNorm(eval) + decoder GEMV + log_softmax.
// ===========================================================================
__global__ __launch_bounds__(128) void k3_out(
    const float* __restrict__ hws,
    const float* __restrict__ dW, const float* __restrict__ db,
    const float* __restrict__ bng, const float* __restrict__ bnb,
    float* __restrict__ out)
{
    __shared__ float hb[H_];
    __shared__ float red[O_];
    const int tid = threadIdx.x;
    const int b = blockIdx.x;
    const float s = 0.9999950000374997f;   // 1/sqrt(1 + 1e-5)
    for (int k = tid; k < H_; k += O_) {
        float v = hws[(size_t)b * H_ + k] * s * bng[k] + bnb[k];
        hb[k] = v;
        out[B_ * O_ + (size_t)b * H_ + k] = v;
    }
    __syncthreads();
    float acc = db[tid];
    #pragma unroll 4
    for (int k = 0; k < H_; ++k) acc += hb[k] * dW[(size_t)k * O_ + tid];
    red[tid] = acc;
    __syncthreads();
    for (int sh = 64; sh > 0; sh >>= 1) {
        if (tid < sh) red[tid] = fmaxf(red[tid], red[tid + sh]);
        __syncthreads();
    }
    float mx = red[0];
    __syncthreads();
    red[tid] = __expf(acc - mx);
    __syncthreads();
    for (int sh = 64; sh > 0; sh >>= 1) {
        if (tid < sh) red[tid] += red[tid + sh];
        __syncthreads();
    }
    float lse = __logf(red[0]) + mx;
    out[(size_t)b * O_ + tid] = acc - lse;
}

extern "C" void kernel_launch(void* const* d_in, const int* in_sizes, int n_in,
                              void* d_out, int out_size, void* d_ws, size_t ws_size,
                              hipStream_t stream)
{
    (void)in_sizes; (void)n_in; (void)out_size; (void)ws_size;
    const float* x   = (const float*)d_in[0];
    const float* dl  = (const float*)d_in[1];
    const float* m   = (const float*)d_in[2];
    const float* xf  = (const float*)d_in[3];
    const float* Wr  = (const float*)d_in[4];
    const float* Ur  = (const float*)d_in[5];
    const float* Vr  = (const float*)d_in[6];
    const float* br  = (const float*)d_in[7];
    const float* Wz  = (const float*)d_in[8];
    const float* Uz  = (const float*)d_in[9];
    const float* Vz  = (const float*)d_in[10];
    const float* bz  = (const float*)d_in[11];
    const float* Wc  = (const float*)d_in[12];
    const float* Uc  = (const float*)d_in[13];
    const float* Vc  = (const float*)d_in[14];
    const float* bc  = (const float*)d_in[15];
    const float* Wgx = (const float*)d_in[16];
    const float* Bgx = (const float*)d_in[17];
    const float* Wgh = (const float*)d_in[18];
    const float* Bgh = (const float*)d_in[19];
    const float* dW  = (const float*)d_in[20];
    const float* db  = (const float*)d_in[21];
    const float* bng = (const float*)d_in[22];
    const float* bnb = (const float*)d_in[23];

    char* p = (char*)d_ws;
    short* PW = (short*)p;              p += (size_t)3 * 256 * 64 * 8 * 2;   // 768 KB
    short* PG = (short*)p;              p += (size_t)128 * 64 * 8 * 2;       // 128 KB
    short* PUc = (short*)p;             p += (size_t)512 * 64 * 8 * 2;       // 512 KB
    unsigned char* PU8 = (unsigned char*)p; p += (size_t)1024 * 64 * 8;      // 512 KB
    bfu* buf0 = (bfu*)p;                p += 4 * SLOTS * 2;                  // 16 MB
    bfu* buf1 = (bfu*)p;                p += 4 * SLOTS * 2;                  // 16 MB
    float* hws = (float*)p;                                                  // 512 KB

    hipMemsetAsync(hws, 0, (size_t)B_ * H_ * sizeof(float), stream);
    k_pack<<<dim3(608), dim3(256), 0, stream>>>(Wz, Wr, Wc, Vz, Vr, Vc, Wgh,
                                                Uz, Ur, Uc, PW, PG, PUc, PU8);
    for (int c = 0; c <= NCH; ++c) {
        k_fused<<<dim3(256), dim3(1024), 0, stream>>>(c,
            x, dl, m, xf, bz, br, bc, Bgh, Wgx, Bgx,
            PW, PG, PUc, PU8, buf0, buf1, hws);
    }
    k3_out<<<dim3(B_), dim3(O_), 0, stream>>>(hws, dW, db, bng, bnb, (float*)d_out);
}